// Round 7
// baseline (530.950 us; speedup 1.0000x reference)
//
#include <hip/hip_runtime.h>
#include <math.h>

#define NPTS 1024
#define DIM 32
#define NPAIR 16   // B*NW

typedef __attribute__((ext_vector_type(8))) short short8;
typedef __attribute__((ext_vector_type(4))) float f32x4;
typedef __attribute__((ext_vector_type(8))) unsigned short ushort8v;
typedef __attribute__((ext_vector_type(4))) unsigned short ushort4v;
typedef unsigned short u16;

__device__ __forceinline__ u16 bf16_rne(float v) {
    unsigned u = __float_as_uint(v);
    return (u16)((u + 0x7fffu + ((u >> 16) & 1u)) >> 16);
}
__device__ __forceinline__ float bf16_to_f32(u16 b) {
    return __uint_as_float(((unsigned)b) << 16);
}

// ============ build X + sqX + XT hi/lo (bf16 transposed) ============
// grid (16 ntiles, NPAIR), block 256
__global__ __launch_bounds__(256) void build_X(const float* __restrict__ pc,
                                               const float* __restrict__ alphas,
                                               float* __restrict__ X,
                                               float* __restrict__ sqX,
                                               u16* __restrict__ hiT,
                                               u16* __restrict__ loT) {
    __shared__ float S[DIM][68];
    int pair = blockIdx.y, n0 = blockIdx.x * 64, tid = threadIdx.x;
    int b = pair >> 2, w = pair & 3;
    for (int e = tid; e < 512; e += 256) {
        int e4 = e * 4;
        int dn = e4 >> 5, dq = e4 & 31;
        float4 p = *(const float4*)&pc[((size_t)b * NPTS + n0 + dn) * DIM + dq];
        float4 al = *(const float4*)&alphas[w * DIM + dq];
        float4 x = make_float4(p.x * al.x, p.y * al.y, p.z * al.z, p.w * al.w);
        *(float4*)&X[((size_t)pair * NPTS + n0 + dn) * DIM + dq] = x;
        S[dq][dn] = x.x; S[dq + 1][dn] = x.y; S[dq + 2][dn] = x.z; S[dq + 3][dn] = x.w;
    }
    __syncthreads();
    if (tid < 64) {
        float s = 0.f;
#pragma unroll
        for (int d = 0; d < DIM; d++) { float v = S[d][tid]; s += v * v; }
        sqX[pair * NPTS + n0 + tid] = s;
    }
    for (int idx = tid; idx < DIM * 4; idx += 256) {
        int row = idx >> 2, nq = (idx & 3) * 16;
        ushort8v hv[2], lv[2];
#pragma unroll
        for (int i = 0; i < 16; i++) {
            float v = S[row][nq + i];
            u16 hb = bf16_rne(v);
            hv[i >> 3][i & 7] = hb;
            lv[i >> 3][i & 7] = bf16_rne(v - bf16_to_f32(hb));
        }
        size_t o = ((size_t)pair * DIM + row) * NPTS + n0 + nq;
        *(ushort8v*)(hiT + o) = hv[0]; *(ushort8v*)(hiT + o + 8) = hv[1];
        *(ushort8v*)(loT + o) = lv[0]; *(ushort8v*)(loT + o + 8) = lv[1];
    }
}

// ============ single-pass W: W bf16 + atomic deg ============
// grid (16 rowtiles, 4 jslices, NPAIR), block 256
__global__ __launch_bounds__(256, 4) void W_kernel(const float* __restrict__ X,
                                                   const float* __restrict__ sqX,
                                                   const float* __restrict__ sigp,
                                                   float* __restrict__ deg,
                                                   u16* __restrict__ Whi) {
    int pair = blockIdx.z;
    int i0 = blockIdx.x * 64, j0 = blockIdx.y * 256;
    float rsig = -1.0f / (*sigp);
    const float* Xp = X + (size_t)pair * NPTS * DIM;

    __shared__ float XiT[DIM][68];
    __shared__ float XjT[DIM][68];
    __shared__ float sqjS[64];

    int tid = threadIdx.x;
    int cx = tid & 15, ry = tid >> 4;

    {
        int r = tid & 63, dgb = (tid >> 6) * 4;
#pragma unroll
        for (int p = 0; p < 2; p++) {
            int dg = dgb + p * 16;
            float4 v = *(const float4*)&Xp[(size_t)(i0 + r) * DIM + dg];
            XiT[dg][r] = v.x; XiT[dg + 1][r] = v.y; XiT[dg + 2][r] = v.z; XiT[dg + 3][r] = v.w;
        }
    }
    float sqi[4];
#pragma unroll
    for (int a = 0; a < 4; a++) sqi[a] = sqX[pair * NPTS + i0 + ry * 4 + a];

    float rs[4] = {0.f, 0.f, 0.f, 0.f};
#pragma unroll 1
    for (int jt = 0; jt < 256; jt += 64) {
        __syncthreads();
        {
            int r = tid & 63, dgb = (tid >> 6) * 4;
#pragma unroll
            for (int p = 0; p < 2; p++) {
                int dg = dgb + p * 16;
                float4 v = *(const float4*)&Xp[(size_t)(j0 + jt + r) * DIM + dg];
                XjT[dg][r] = v.x; XjT[dg + 1][r] = v.y; XjT[dg + 2][r] = v.z; XjT[dg + 3][r] = v.w;
            }
        }
        if (tid < 64) sqjS[tid] = sqX[pair * NPTS + j0 + jt + tid];
        __syncthreads();

        float dot[4][4] = {};
#pragma unroll
        for (int d = 0; d < DIM; d++) {
            float4 a = *(const float4*)&XiT[d][ry * 4];
            float4 b = *(const float4*)&XjT[d][cx * 4];
            dot[0][0] += a.x * b.x; dot[0][1] += a.x * b.y; dot[0][2] += a.x * b.z; dot[0][3] += a.x * b.w;
            dot[1][0] += a.y * b.x; dot[1][1] += a.y * b.y; dot[1][2] += a.y * b.z; dot[1][3] += a.y * b.w;
            dot[2][0] += a.z * b.x; dot[2][1] += a.z * b.y; dot[2][2] += a.z * b.z; dot[2][3] += a.z * b.w;
            dot[3][0] += a.w * b.x; dot[3][1] += a.w * b.y; dot[3][2] += a.w * b.z; dot[3][3] += a.w * b.w;
        }
#pragma unroll
        for (int a = 0; a < 4; a++) {
            int i = i0 + ry * 4 + a;
            int jb = j0 + jt + cx * 4;
            ushort4v hv;
#pragma unroll
            for (int bb = 0; bb < 4; bb++) {
                float Dm = sqi[a] + sqjS[cx * 4 + bb] - 2.0f * dot[a][bb];
                float K = __expf(Dm * rsig);
                float Wv = (K >= 0.5f) ? K : 0.0f;
                rs[a] += Wv;
                hv[bb] = bf16_rne(Wv);
            }
            *(ushort4v*)(Whi + ((size_t)pair * NPTS + i) * NPTS + jb) = hv;
        }
    }
#pragma unroll
    for (int a = 0; a < 4; a++) {
        float s = rs[a];
        s += __shfl_xor(s, 1); s += __shfl_xor(s, 2);
        s += __shfl_xor(s, 4); s += __shfl_xor(s, 8);
        if (cx == 0) atomicAdd(&deg[pair * NPTS + i0 + ry * 4 + a], s);
    }
}

// ============ fused apply: O = 0.5*Y + (0.5/deg)*(W@Y); 16-row tiles, k-split=8 ============
// grid (64 rowtiles, NPAIR), block 512 (8 waves; wave w owns k-eighth w, one 16-row m-tile)
template <int DC>
__global__ __launch_bounds__(512, (DC == 32 ? 8 : (DC == 64 ? 6 : 4)))
void apply_fused(const u16* __restrict__ Whi,
                 const u16* __restrict__ Yhi,
                 const u16* __restrict__ Ylo,
                 const float* __restrict__ deg,
                 const float* __restrict__ prevF,
                 int prevStride, int prevOff,
                 float* __restrict__ dstF,
                 int dstStride, int dstOff,
                 float* __restrict__ sliceF,  // cols 32..63 -> stride 32
                 u16* __restrict__ hiT, u16* __restrict__ loT,
                 int tC0, int tCN) {
    constexpr int NT = DC / 16;
    constexpr int SP = DC + 4;   // 4*SP % 32 == 16 -> phase-1 quad stride lands on alt bank half (2-way, free)
    __shared__ float S[4][16][SP];
    __shared__ float rdegS[16];
    int pair = blockIdx.y;
    int r0 = blockIdx.x * 16;
    int tid = threadIdx.x;
    int wv = tid >> 6, lane = tid & 63;
    int m = lane & 15, quad = lane >> 4;
    int kb = wv * 128;

    if (tid < 16) rdegS[tid] = 0.5f / deg[pair * NPTS + r0 + tid];

    size_t aoff = ((size_t)pair * NPTS + r0 + m) * NPTS + kb + quad * 8;
    size_t boff = ((size_t)pair * DC + m) * NPTS + kb + quad * 8;

    f32x4 acc[NT];
#pragma unroll
    for (int nt = 0; nt < NT; nt++)
#pragma unroll
        for (int i = 0; i < 4; i++) acc[nt][i] = 0.0f;

#pragma unroll 2
    for (int c = 0; c < 4; c++) {
        int ko = c * 32;
        short8 ah = *(const short8*)(Whi + aoff + ko);
#pragma unroll
        for (int nt = 0; nt < NT; nt++) {
            short8 bh = *(const short8*)(Yhi + boff + (size_t)nt * 16 * NPTS + ko);
            short8 bl = *(const short8*)(Ylo + boff + (size_t)nt * 16 * NPTS + ko);
            acc[nt] = __builtin_amdgcn_mfma_f32_16x16x32_bf16(ah, bh, acc[nt], 0, 0, 0);
            acc[nt] = __builtin_amdgcn_mfma_f32_16x16x32_bf16(ah, bl, acc[nt], 0, 0, 0);
        }
    }

    // phase 1a: waves 0-3 deposit partial tiles (C layout: row=quad*4+i, col=nt*16+m)
    if (wv < 4) {
#pragma unroll
        for (int nt = 0; nt < NT; nt++)
#pragma unroll
            for (int i = 0; i < 4; i++)
                S[wv][quad * 4 + i][nt * 16 + m] = acc[nt][i];
    }
    __syncthreads();
    // phase 1b: waves 4-7 add into planes 0-3 (cell-aligned: same lane mapping)
    if (wv >= 4) {
#pragma unroll
        for (int nt = 0; nt < NT; nt++)
#pragma unroll
            for (int i = 0; i < 4; i++)
                S[wv - 4][quad * 4 + i][nt * 16 + m] += acc[nt][i];
    }
    __syncthreads();

    // phase 2: sum planes, epilogue O = 0.5*prev + rdeg*sum, write fp32, stash in S[0]
    constexpr int E2 = 16 * DC / 4;
    for (int e = tid; e < E2; e += 512) {
        int e4 = e * 4;
        int n = e4 / DC, d = e4 % DC;
        float4 s0 = *(const float4*)&S[0][n][d];
        float4 s1 = *(const float4*)&S[1][n][d];
        float4 s2 = *(const float4*)&S[2][n][d];
        float4 s3 = *(const float4*)&S[3][n][d];
        float4 pv = *(const float4*)&prevF[((size_t)pair * NPTS + r0 + n) * prevStride + prevOff + d];
        float r = rdegS[n];
        float4 o = make_float4(0.5f * pv.x + r * (s0.x + s1.x + s2.x + s3.x),
                               0.5f * pv.y + r * (s0.y + s1.y + s2.y + s3.y),
                               0.5f * pv.z + r * (s0.z + s1.z + s2.z + s3.z),
                               0.5f * pv.w + r * (s0.w + s1.w + s2.w + s3.w));
        *(float4*)&dstF[((size_t)pair * NPTS + r0 + n) * dstStride + dstOff + d] = o;
        if (sliceF && d >= 32 && d < 64)
            *(float4*)&sliceF[((size_t)pair * NPTS + r0 + n) * 32 + (d - 32)] = o;
        *(float4*)&S[0][n][d] = o;
    }
    __syncthreads();

    // phase 3: transposed bf16 hi/lo operand for the next step (16 n-values -> 2 vec8 per row)
    if (hiT) {
        for (int e = tid; e < tCN * 2; e += 512) {
            int row = e >> 1, nq = (e & 1) * 8;
            ushort8v hv, lv;
#pragma unroll
            for (int j = 0; j < 8; j++) {
                float v = S[0][nq + j][tC0 + row];
                u16 hb = bf16_rne(v);
                hv[j] = hb;
                lv[j] = bf16_rne(v - bf16_to_f32(hb));
            }
            size_t o = ((size_t)pair * tCN + row) * NPTS + r0 + nq;
            *(ushort8v*)(hiT + o) = hv;
            *(ushort8v*)(loT + o) = lv;
        }
    }
}

// ============ build M0 cols 32..95 fp32 + full M0T hi/lo ============
// grid (16 ntiles, NPAIR), block 256
__global__ __launch_bounds__(256) void build_M0(const float* __restrict__ A1,
                                                const float* __restrict__ A2,
                                                float* __restrict__ M0,
                                                u16* __restrict__ hiT,
                                                u16* __restrict__ loT) {
    __shared__ float S[96][68];
    int pair = blockIdx.y, n0 = blockIdx.x * 64, tid = threadIdx.x;
    for (int e = tid; e < 512; e += 256) {
        int e4 = e * 4;
        int dn = e4 >> 5, dq = e4 & 31;
        size_t pn = (size_t)pair * NPTS + n0 + dn;
        float4 a1 = *(const float4*)&A1[pn * 32 + dq];
        float4 a2 = *(const float4*)&A2[pn * 32 + dq];
        float4 t4 = *(const float4*)&M0[pn * 96 + dq];
        float4 f0 = make_float4(fabsf(a1.x - a2.x), fabsf(a1.y - a2.y), fabsf(a1.z - a2.z), fabsf(a1.w - a2.w));
        float4 f1 = make_float4(fabsf(a2.x - t4.x), fabsf(a2.y - t4.y), fabsf(a2.z - t4.z), fabsf(a2.w - t4.w));
        *(float4*)&M0[pn * 96 + 32 + dq] = f0;
        *(float4*)&M0[pn * 96 + 64 + dq] = f1;
        S[dq][dn] = t4.x; S[dq + 1][dn] = t4.y; S[dq + 2][dn] = t4.z; S[dq + 3][dn] = t4.w;
        S[32 + dq][dn] = f0.x; S[33 + dq][dn] = f0.y; S[34 + dq][dn] = f0.z; S[35 + dq][dn] = f0.w;
        S[64 + dq][dn] = f1.x; S[65 + dq][dn] = f1.y; S[66 + dq][dn] = f1.z; S[67 + dq][dn] = f1.w;
    }
    __syncthreads();
    for (int idx = tid; idx < 96 * 4; idx += 256) {
        int row = idx >> 2, nq = (idx & 3) * 16;
        ushort8v hv[2], lv[2];
#pragma unroll
        for (int i = 0; i < 16; i++) {
            float v = S[row][nq + i];
            u16 hb = bf16_rne(v);
            hv[i >> 3][i & 7] = hb;
            lv[i >> 3][i & 7] = bf16_rne(v - bf16_to_f32(hb));
        }
        size_t o = ((size_t)pair * 96 + row) * NPTS + n0 + nq;
        *(ushort8v*)(hiT + o) = hv[0]; *(ushort8v*)(hiT + o + 8) = hv[1];
        *(ushort8v*)(loT + o) = lv[0]; *(ushort8v*)(loT + o + 8) = lv[1];
    }
}

// ============ pooling: grid (7, NPAIR, 8 nslices), block (32,8), atomic accumulate ============
__global__ __launch_bounds__(256) void pool_kernel(const float* __restrict__ X,
                                                   const float* __restrict__ M0,
                                                   const float* __restrict__ M2p,
                                                   const float* __restrict__ M4,
                                                   const float* __restrict__ Z8,
                                                   float* __restrict__ out) {
    int g = blockIdx.x;
    int pair = blockIdx.y;
    int sl = blockIdx.z;
    int d = threadIdx.x;
    int ty = threadIdx.y;
    float s = 0.0f;
    int nend = sl * 128 + 128;
    for (int n = sl * 128 + ty; n < nend; n += 8) {
        size_t pn = (size_t)pair * NPTS + n;
        float v = 0.0f;
        switch (g) {
            case 0: v = X[pn * 32 + d]; break;
            case 1: v = M0[pn * 96 + 32 + d]; break;
            case 2: v = M0[pn * 96 + 64 + d]; break;
            case 3: v = fabsf(M0[pn * 96 + d] - M4[pn * 96 + d]); break;
            case 4: v = fabsf(M2p[pn * 32 + d] - M4[pn * 96 + 32 + d]); break;
            case 5: v = fabsf(M4[pn * 96 + 32 + d] - Z8[pn * 64 + d]); break;
            case 6: v = fabsf(M4[pn * 96 + 64 + d] - Z8[pn * 64 + 32 + d]); break;
        }
        s += v;
    }
    __shared__ float red[8][33];
    red[ty][d] = s;
    __syncthreads();
    if (ty == 0) {
        float tot = 0.0f;
#pragma unroll
        for (int t = 0; t < 8; t++) tot += red[t][d];
        atomicAdd(&out[(size_t)pair * 224 + g * 32 + d], tot * (1.0f / 1024.0f));
    }
}

extern "C" void kernel_launch(void* const* d_in, const int* in_sizes, int n_in,
                              void* d_out, int out_size, void* d_ws, size_t ws_size,
                              hipStream_t stream) {
    const float* pc     = (const float*)d_in[0];
    const float* alphas = (const float*)d_in[1];
    const float* sigp   = (const float*)d_in[2];
    float* out = (float*)d_out;
    float* ws = (float*)d_ws;

    // ---- workspace layout (~84 MB) ----
    float* X    = ws;                         // 524288
    float* sqX  = X + 524288;                 // 16384
    float* deg  = sqX + 16384;                // 16384
    u16* Whi = (u16*)(deg + 16384);           // 16777216 u16
    // region overlaid by F96b during M/N chains:
    float* A1   = (float*)(Whi + 16777216);   // 524288
    float* A2   = A1 + 524288;                // 524288
    u16* T32a_h = (u16*)(A2 + 524288);        // 524288 u16 each
    u16* T32a_l = T32a_h + 524288;
    u16* T32b_h = T32a_l + 524288;
    u16* T32b_l = T32b_h + 524288;
    float* F96b = A1;                         // overlay (A1,A2,T32a_h/l dead by then)
    // ----
    float* M0   = (float*)(T32b_l + 524288);  // 1572864
    float* M2p  = M0 + 1572864;               // 524288 (cols 32..63 of M2)
    float* M4f  = M2p + 524288;               // 1572864
    float* Z8   = M4f + 1572864;              // 1048576
    float* F96a = Z8 + 1048576;               // 1572864  (also A3 overlay before M-chain)
    float* A3   = F96a;
    u16* T96a_h = (u16*)(F96a + 1572864);     // 1572864 u16 each
    u16* T96a_l = T96a_h + 1572864;
    u16* T96b_h = T96a_l + 1572864;
    u16* T96b_l = T96b_h + 1572864;
    u16* T64a_h = T96a_h;
    u16* T64a_l = T96a_l;
    u16* T64b_h = T96b_h;
    u16* T64b_l = T96b_l;

    dim3 b256(256), b512(512);
    dim3 gA(64, NPAIR);

    build_X<<<dim3(16, NPAIR), b256, 0, stream>>>(pc, alphas, X, sqX, T32a_h, T32a_l);
    hipMemsetAsync(deg, 0, 16384 * sizeof(float), stream);
    W_kernel<<<dim3(16, 4, NPAIR), b256, 0, stream>>>(X, sqX, sigp, deg, Whi);

    // ---- A-chain (D=32): A1, A2, A3, A4 -> M0 cols 0..31 ----
    apply_fused<32><<<gA, b512, 0, stream>>>(Whi, T32a_h, T32a_l, deg,
                                             X, 32, 0, A1, 32, 0, nullptr, T32b_h, T32b_l, 0, 32);
    apply_fused<32><<<gA, b512, 0, stream>>>(Whi, T32b_h, T32b_l, deg,
                                             A1, 32, 0, A2, 32, 0, nullptr, T32a_h, T32a_l, 0, 32);
    apply_fused<32><<<gA, b512, 0, stream>>>(Whi, T32a_h, T32a_l, deg,
                                             A2, 32, 0, A3, 32, 0, nullptr, T32b_h, T32b_l, 0, 32);
    apply_fused<32><<<gA, b512, 0, stream>>>(Whi, T32b_h, T32b_l, deg,
                                             A3, 32, 0, M0, 96, 0, nullptr, nullptr, nullptr, 0, 32);

    build_M0<<<dim3(16, NPAIR), b256, 0, stream>>>(A1, A2, M0, T96a_h, T96a_l);

    // ---- M-chain (D=96): M4 = P^4 M0; M2 cols 32..63 saved to M2p ----
    apply_fused<96><<<gA, b512, 0, stream>>>(Whi, T96a_h, T96a_l, deg,
                                             M0, 96, 0, F96a, 96, 0, nullptr, T96b_h, T96b_l, 0, 96);
    apply_fused<96><<<gA, b512, 0, stream>>>(Whi, T96b_h, T96b_l, deg,
                                             F96a, 96, 0, F96b, 96, 0, M2p, T96a_h, T96a_l, 0, 96);
    apply_fused<96><<<gA, b512, 0, stream>>>(Whi, T96a_h, T96a_l, deg,
                                             F96b, 96, 0, F96a, 96, 0, nullptr, T96b_h, T96b_l, 0, 96);
    apply_fused<96><<<gA, b512, 0, stream>>>(Whi, T96b_h, T96b_l, deg,
                                             F96a, 96, 0, M4f, 96, 0, nullptr, T64a_h, T64a_l, 32, 64);

    // ---- N-chain (D=64): Z8 = P^4 (M4 cols 32..95) ----
    apply_fused<64><<<gA, b512, 0, stream>>>(Whi, T64a_h, T64a_l, deg,
                                             M4f, 96, 32, F96a, 64, 0, nullptr, T64b_h, T64b_l, 0, 64);
    apply_fused<64><<<gA, b512, 0, stream>>>(Whi, T64b_h, T64b_l, deg,
                                             F96a, 64, 0, F96b, 64, 0, nullptr, T64a_h, T64a_l, 0, 64);
    apply_fused<64><<<gA, b512, 0, stream>>>(Whi, T64a_h, T64a_l, deg,
                                             F96b, 64, 0, F96a, 64, 0, nullptr, T64b_h, T64b_l, 0, 64);
    apply_fused<64><<<gA, b512, 0, stream>>>(Whi, T64b_h, T64b_l, deg,
                                             F96a, 64, 0, Z8, 64, 0, nullptr, nullptr, nullptr, 0, 64);

    hipMemsetAsync(out, 0, (size_t)NPAIR * 224 * sizeof(float), stream);
    pool_kernel<<<dim3(7, NPAIR, 8), dim3(32, 8), 0, stream>>>(X, M0, M2p, M4f, Z8, out);
}

// Round 8
// 371.785 us; speedup vs baseline: 1.4281x; 1.4281x over previous
//
#include <hip/hip_runtime.h>
#include <math.h>

#define NPTS 1024
#define DIM 32
#define NPAIR 16   // B*NW

typedef __attribute__((ext_vector_type(8))) short short8;
typedef __attribute__((ext_vector_type(4))) float f32x4;
typedef __attribute__((ext_vector_type(8))) unsigned short ushort8v;
typedef __attribute__((ext_vector_type(4))) unsigned short ushort4v;
typedef unsigned short u16;

__device__ __forceinline__ u16 bf16_rne(float v) {
    unsigned u = __float_as_uint(v);
    return (u16)((u + 0x7fffu + ((u >> 16) & 1u)) >> 16);
}
__device__ __forceinline__ float bf16_to_f32(u16 b) {
    return __uint_as_float(((unsigned)b) << 16);
}

// ============ build X + sqX + XT hi/lo (bf16 transposed) ============
// grid (16 ntiles, NPAIR), block 256
__global__ __launch_bounds__(256) void build_X(const float* __restrict__ pc,
                                               const float* __restrict__ alphas,
                                               float* __restrict__ X,
                                               float* __restrict__ sqX,
                                               u16* __restrict__ hiT,
                                               u16* __restrict__ loT) {
    __shared__ float S[DIM][68];
    int pair = blockIdx.y, n0 = blockIdx.x * 64, tid = threadIdx.x;
    int b = pair >> 2, w = pair & 3;
    for (int e = tid; e < 512; e += 256) {
        int e4 = e * 4;
        int dn = e4 >> 5, dq = e4 & 31;
        float4 p = *(const float4*)&pc[((size_t)b * NPTS + n0 + dn) * DIM + dq];
        float4 al = *(const float4*)&alphas[w * DIM + dq];
        float4 x = make_float4(p.x * al.x, p.y * al.y, p.z * al.z, p.w * al.w);
        *(float4*)&X[((size_t)pair * NPTS + n0 + dn) * DIM + dq] = x;
        S[dq][dn] = x.x; S[dq + 1][dn] = x.y; S[dq + 2][dn] = x.z; S[dq + 3][dn] = x.w;
    }
    __syncthreads();
    if (tid < 64) {
        float s = 0.f;
#pragma unroll
        for (int d = 0; d < DIM; d++) { float v = S[d][tid]; s += v * v; }
        sqX[pair * NPTS + n0 + tid] = s;
    }
    for (int idx = tid; idx < DIM * 4; idx += 256) {
        int row = idx >> 2, nq = (idx & 3) * 16;
        ushort8v hv[2], lv[2];
#pragma unroll
        for (int i = 0; i < 16; i++) {
            float v = S[row][nq + i];
            u16 hb = bf16_rne(v);
            hv[i >> 3][i & 7] = hb;
            lv[i >> 3][i & 7] = bf16_rne(v - bf16_to_f32(hb));
        }
        size_t o = ((size_t)pair * DIM + row) * NPTS + n0 + nq;
        *(ushort8v*)(hiT + o) = hv[0]; *(ushort8v*)(hiT + o + 8) = hv[1];
        *(ushort8v*)(loT + o) = lv[0]; *(ushort8v*)(loT + o + 8) = lv[1];
    }
}

// ============ single-pass W: W bf16 + atomic deg; XCD-pinned 1D grid ============
// grid 1024 blocks flat: xcd = b&7 -> pair = xcd*2 + (loc&1); block 256
__global__ __launch_bounds__(256, 4) void W_kernel(const float* __restrict__ X,
                                                   const float* __restrict__ sqX,
                                                   const float* __restrict__ sigp,
                                                   float* __restrict__ deg,
                                                   u16* __restrict__ Whi) {
    int bid = blockIdx.x;
    int xcd = bid & 7, loc = bid >> 3;          // loc 0..127
    int pair = xcd * 2 + (loc & 1);
    int j0 = ((loc >> 1) & 3) * 256;
    int i0 = (loc >> 3) * 64;
    float rsig = -1.0f / (*sigp);
    const float* Xp = X + (size_t)pair * NPTS * DIM;

    __shared__ float XiT[DIM][68];
    __shared__ float XjT[DIM][68];
    __shared__ float sqjS[64];

    int tid = threadIdx.x;
    int cx = tid & 15, ry = tid >> 4;

    {
        int r = tid & 63, dgb = (tid >> 6) * 4;
#pragma unroll
        for (int p = 0; p < 2; p++) {
            int dg = dgb + p * 16;
            float4 v = *(const float4*)&Xp[(size_t)(i0 + r) * DIM + dg];
            XiT[dg][r] = v.x; XiT[dg + 1][r] = v.y; XiT[dg + 2][r] = v.z; XiT[dg + 3][r] = v.w;
        }
    }
    float sqi[4];
#pragma unroll
    for (int a = 0; a < 4; a++) sqi[a] = sqX[pair * NPTS + i0 + ry * 4 + a];

    float rs[4] = {0.f, 0.f, 0.f, 0.f};
#pragma unroll 1
    for (int jt = 0; jt < 256; jt += 64) {
        __syncthreads();
        {
            int r = tid & 63, dgb = (tid >> 6) * 4;
#pragma unroll
            for (int p = 0; p < 2; p++) {
                int dg = dgb + p * 16;
                float4 v = *(const float4*)&Xp[(size_t)(j0 + jt + r) * DIM + dg];
                XjT[dg][r] = v.x; XjT[dg + 1][r] = v.y; XjT[dg + 2][r] = v.z; XjT[dg + 3][r] = v.w;
            }
        }
        if (tid < 64) sqjS[tid] = sqX[pair * NPTS + j0 + jt + tid];
        __syncthreads();

        float dot[4][4] = {};
#pragma unroll
        for (int d = 0; d < DIM; d++) {
            float4 a = *(const float4*)&XiT[d][ry * 4];
            float4 b = *(const float4*)&XjT[d][cx * 4];
            dot[0][0] += a.x * b.x; dot[0][1] += a.x * b.y; dot[0][2] += a.x * b.z; dot[0][3] += a.x * b.w;
            dot[1][0] += a.y * b.x; dot[1][1] += a.y * b.y; dot[1][2] += a.y * b.z; dot[1][3] += a.y * b.w;
            dot[2][0] += a.z * b.x; dot[2][1] += a.z * b.y; dot[2][2] += a.z * b.z; dot[2][3] += a.z * b.w;
            dot[3][0] += a.w * b.x; dot[3][1] += a.w * b.y; dot[3][2] += a.w * b.z; dot[3][3] += a.w * b.w;
        }
#pragma unroll
        for (int a = 0; a < 4; a++) {
            int i = i0 + ry * 4 + a;
            int jb = j0 + jt + cx * 4;
            ushort4v hv;
#pragma unroll
            for (int bb = 0; bb < 4; bb++) {
                float Dm = sqi[a] + sqjS[cx * 4 + bb] - 2.0f * dot[a][bb];
                float K = __expf(Dm * rsig);
                float Wv = (K >= 0.5f) ? K : 0.0f;
                rs[a] += Wv;
                hv[bb] = bf16_rne(Wv);
            }
            *(ushort4v*)(Whi + ((size_t)pair * NPTS + i) * NPTS + jb) = hv;
        }
    }
#pragma unroll
    for (int a = 0; a < 4; a++) {
        float s = rs[a];
        s += __shfl_xor(s, 1); s += __shfl_xor(s, 2);
        s += __shfl_xor(s, 4); s += __shfl_xor(s, 8);
        if (cx == 0) atomicAdd(&deg[pair * NPTS + i0 + ry * 4 + a], s);
    }
}

// ============ fused apply: O = 0.5*Y + (0.5/deg)*(W@Y); 32-row tiles, k-split=8, XCD-pinned ============
// grid 512 blocks flat (pair = (b&7)*2 + ((b>>3)&1), rowtile = b>>4), block 512
template <int DC>
__global__ __launch_bounds__(512, 4) void apply_fused(const u16* __restrict__ Whi,
                                                      const u16* __restrict__ Yhi,
                                                      const u16* __restrict__ Ylo,
                                                      const float* __restrict__ deg,
                                                      const float* __restrict__ prevF,
                                                      int prevStride, int prevOff,
                                                      float* __restrict__ dstF,
                                                      int dstStride, int dstOff,
                                                      float* __restrict__ sliceF,  // cols 32..63 -> stride 32
                                                      u16* __restrict__ hiT, u16* __restrict__ loT,
                                                      int tC0, int tCN) {
    constexpr int NT = DC / 16;
    constexpr int SP = DC + 4;   // 4*SP % 32 == 16 -> quad stride hits alternate bank half (2-way, free)
    __shared__ float S[4][32][SP];
    __shared__ float rdegS[32];
    int bid = blockIdx.x;
    int pair = (bid & 7) * 2 + ((bid >> 3) & 1);
    int r0 = (bid >> 4) * 32;
    int tid = threadIdx.x;
    int wv = tid >> 6, lane = tid & 63;
    int m = lane & 15, quad = lane >> 4;
    int kb = wv * 128;

    if (tid < 32) rdegS[tid] = 0.5f / deg[pair * NPTS + r0 + tid];

    size_t aoff = ((size_t)pair * NPTS + r0 + m) * NPTS + kb + quad * 8;
    size_t boff = ((size_t)pair * DC + m) * NPTS + kb + quad * 8;

    f32x4 acc[2][NT];
#pragma unroll
    for (int mt = 0; mt < 2; mt++)
#pragma unroll
        for (int nt = 0; nt < NT; nt++)
#pragma unroll
            for (int i = 0; i < 4; i++) acc[mt][nt][i] = 0.0f;

#pragma unroll 2
    for (int c = 0; c < 4; c++) {
        int ko = c * 32;
        short8 a0h = *(const short8*)(Whi + aoff + ko);
        short8 a1h = *(const short8*)(Whi + aoff + 16 * NPTS + ko);
#pragma unroll
        for (int nt = 0; nt < NT; nt++) {
            short8 bh = *(const short8*)(Yhi + boff + (size_t)nt * 16 * NPTS + ko);
            short8 bl = *(const short8*)(Ylo + boff + (size_t)nt * 16 * NPTS + ko);
            acc[0][nt] = __builtin_amdgcn_mfma_f32_16x16x32_bf16(a0h, bh, acc[0][nt], 0, 0, 0);
            acc[0][nt] = __builtin_amdgcn_mfma_f32_16x16x32_bf16(a0h, bl, acc[0][nt], 0, 0, 0);
            acc[1][nt] = __builtin_amdgcn_mfma_f32_16x16x32_bf16(a1h, bh, acc[1][nt], 0, 0, 0);
            acc[1][nt] = __builtin_amdgcn_mfma_f32_16x16x32_bf16(a1h, bl, acc[1][nt], 0, 0, 0);
        }
    }

    // phase 1a: waves 0-3 deposit partial tiles
    if (wv < 4) {
#pragma unroll
        for (int mt = 0; mt < 2; mt++)
#pragma unroll
            for (int nt = 0; nt < NT; nt++)
#pragma unroll
                for (int i = 0; i < 4; i++)
                    S[wv][mt * 16 + quad * 4 + i][nt * 16 + m] = acc[mt][nt][i];
    }
    __syncthreads();
    // phase 1b: waves 4-7 add into planes 0-3
    if (wv >= 4) {
#pragma unroll
        for (int mt = 0; mt < 2; mt++)
#pragma unroll
            for (int nt = 0; nt < NT; nt++)
#pragma unroll
                for (int i = 0; i < 4; i++)
                    S[wv - 4][mt * 16 + quad * 4 + i][nt * 16 + m] += acc[mt][nt][i];
    }
    __syncthreads();

    // phase 2: sum planes, epilogue O = 0.5*prev + rdeg*sum, write fp32, stash in S[0]
    constexpr int E2 = 32 * DC / 4;
    for (int e = tid; e < E2; e += 512) {
        int e4 = e * 4;
        int n = e4 / DC, d = e4 % DC;
        float4 s0 = *(const float4*)&S[0][n][d];
        float4 s1 = *(const float4*)&S[1][n][d];
        float4 s2 = *(const float4*)&S[2][n][d];
        float4 s3 = *(const float4*)&S[3][n][d];
        float4 pv = *(const float4*)&prevF[((size_t)pair * NPTS + r0 + n) * prevStride + prevOff + d];
        float r = rdegS[n];
        float4 o = make_float4(0.5f * pv.x + r * (s0.x + s1.x + s2.x + s3.x),
                               0.5f * pv.y + r * (s0.y + s1.y + s2.y + s3.y),
                               0.5f * pv.z + r * (s0.z + s1.z + s2.z + s3.z),
                               0.5f * pv.w + r * (s0.w + s1.w + s2.w + s3.w));
        *(float4*)&dstF[((size_t)pair * NPTS + r0 + n) * dstStride + dstOff + d] = o;
        if (sliceF && d >= 32 && d < 64)
            *(float4*)&sliceF[((size_t)pair * NPTS + r0 + n) * 32 + (d - 32)] = o;
        *(float4*)&S[0][n][d] = o;
    }
    __syncthreads();

    // phase 3: transposed bf16 hi/lo operand for the next step
    if (hiT) {
        for (int e = tid; e < tCN * 4; e += 512) {
            int row = e >> 2, nq = (e & 3) * 8;
            ushort8v hv, lv;
#pragma unroll
            for (int j = 0; j < 8; j++) {
                float v = S[0][nq + j][tC0 + row];
                u16 hb = bf16_rne(v);
                hv[j] = hb;
                lv[j] = bf16_rne(v - bf16_to_f32(hb));
            }
            size_t o = ((size_t)pair * tCN + row) * NPTS + r0 + nq;
            *(ushort8v*)(hiT + o) = hv;
            *(ushort8v*)(loT + o) = lv;
        }
    }
}

// ============ build M0 cols 32..95 fp32 + full M0T hi/lo ============
// grid (16 ntiles, NPAIR), block 256
__global__ __launch_bounds__(256) void build_M0(const float* __restrict__ A1,
                                                const float* __restrict__ A2,
                                                float* __restrict__ M0,
                                                u16* __restrict__ hiT,
                                                u16* __restrict__ loT) {
    __shared__ float S[96][68];
    int pair = blockIdx.y, n0 = blockIdx.x * 64, tid = threadIdx.x;
    for (int e = tid; e < 512; e += 256) {
        int e4 = e * 4;
        int dn = e4 >> 5, dq = e4 & 31;
        size_t pn = (size_t)pair * NPTS + n0 + dn;
        float4 a1 = *(const float4*)&A1[pn * 32 + dq];
        float4 a2 = *(const float4*)&A2[pn * 32 + dq];
        float4 t4 = *(const float4*)&M0[pn * 96 + dq];
        float4 f0 = make_float4(fabsf(a1.x - a2.x), fabsf(a1.y - a2.y), fabsf(a1.z - a2.z), fabsf(a1.w - a2.w));
        float4 f1 = make_float4(fabsf(a2.x - t4.x), fabsf(a2.y - t4.y), fabsf(a2.z - t4.z), fabsf(a2.w - t4.w));
        *(float4*)&M0[pn * 96 + 32 + dq] = f0;
        *(float4*)&M0[pn * 96 + 64 + dq] = f1;
        S[dq][dn] = t4.x; S[dq + 1][dn] = t4.y; S[dq + 2][dn] = t4.z; S[dq + 3][dn] = t4.w;
        S[32 + dq][dn] = f0.x; S[33 + dq][dn] = f0.y; S[34 + dq][dn] = f0.z; S[35 + dq][dn] = f0.w;
        S[64 + dq][dn] = f1.x; S[65 + dq][dn] = f1.y; S[66 + dq][dn] = f1.z; S[67 + dq][dn] = f1.w;
    }
    __syncthreads();
    for (int idx = tid; idx < 96 * 4; idx += 256) {
        int row = idx >> 2, nq = (idx & 3) * 16;
        ushort8v hv[2], lv[2];
#pragma unroll
        for (int i = 0; i < 16; i++) {
            float v = S[row][nq + i];
            u16 hb = bf16_rne(v);
            hv[i >> 3][i & 7] = hb;
            lv[i >> 3][i & 7] = bf16_rne(v - bf16_to_f32(hb));
        }
        size_t o = ((size_t)pair * 96 + row) * NPTS + n0 + nq;
        *(ushort8v*)(hiT + o) = hv[0]; *(ushort8v*)(hiT + o + 8) = hv[1];
        *(ushort8v*)(loT + o) = lv[0]; *(ushort8v*)(loT + o + 8) = lv[1];
    }
}

// ============ pooling: grid (7, NPAIR, 8 nslices), block (32,8), atomic accumulate ============
__global__ __launch_bounds__(256) void pool_kernel(const float* __restrict__ X,
                                                   const float* __restrict__ M0,
                                                   const float* __restrict__ M2p,
                                                   const float* __restrict__ M4,
                                                   const float* __restrict__ Z8,
                                                   float* __restrict__ out) {
    int g = blockIdx.x;
    int pair = blockIdx.y;
    int sl = blockIdx.z;
    int d = threadIdx.x;
    int ty = threadIdx.y;
    float s = 0.0f;
    int nend = sl * 128 + 128;
    for (int n = sl * 128 + ty; n < nend; n += 8) {
        size_t pn = (size_t)pair * NPTS + n;
        float v = 0.0f;
        switch (g) {
            case 0: v = X[pn * 32 + d]; break;
            case 1: v = M0[pn * 96 + 32 + d]; break;
            case 2: v = M0[pn * 96 + 64 + d]; break;
            case 3: v = fabsf(M0[pn * 96 + d] - M4[pn * 96 + d]); break;
            case 4: v = fabsf(M2p[pn * 32 + d] - M4[pn * 96 + 32 + d]); break;
            case 5: v = fabsf(M4[pn * 96 + 32 + d] - Z8[pn * 64 + d]); break;
            case 6: v = fabsf(M4[pn * 96 + 64 + d] - Z8[pn * 64 + 32 + d]); break;
        }
        s += v;
    }
    __shared__ float red[8][33];
    red[ty][d] = s;
    __syncthreads();
    if (ty == 0) {
        float tot = 0.0f;
#pragma unroll
        for (int t = 0; t < 8; t++) tot += red[t][d];
        atomicAdd(&out[(size_t)pair * 224 + g * 32 + d], tot * (1.0f / 1024.0f));
    }
}

extern "C" void kernel_launch(void* const* d_in, const int* in_sizes, int n_in,
                              void* d_out, int out_size, void* d_ws, size_t ws_size,
                              hipStream_t stream) {
    const float* pc     = (const float*)d_in[0];
    const float* alphas = (const float*)d_in[1];
    const float* sigp   = (const float*)d_in[2];
    float* out = (float*)d_out;
    float* ws = (float*)d_ws;

    // ---- workspace layout (~84 MB) ----
    float* X    = ws;                         // 524288
    float* sqX  = X + 524288;                 // 16384
    float* deg  = sqX + 16384;                // 16384
    u16* Whi = (u16*)(deg + 16384);           // 16777216 u16
    // region overlaid by F96b during M/N chains:
    float* A1   = (float*)(Whi + 16777216);   // 524288
    float* A2   = A1 + 524288;                // 524288
    u16* T32a_h = (u16*)(A2 + 524288);        // 524288 u16 each
    u16* T32a_l = T32a_h + 524288;
    u16* T32b_h = T32a_l + 524288;
    u16* T32b_l = T32b_h + 524288;
    float* F96b = A1;                         // overlay (A1,A2,T32a_h/l dead by then)
    // ----
    float* M0   = (float*)(T32b_l + 524288);  // 1572864
    float* M2p  = M0 + 1572864;               // 524288 (cols 32..63 of M2)
    float* M4f  = M2p + 524288;               // 1572864
    float* Z8   = M4f + 1572864;              // 1048576
    float* F96a = Z8 + 1048576;               // 1572864  (also A3 overlay before M-chain)
    float* A3   = F96a;
    u16* T96a_h = (u16*)(F96a + 1572864);     // 1572864 u16 each
    u16* T96a_l = T96a_h + 1572864;
    u16* T96b_h = T96a_l + 1572864;
    u16* T96b_l = T96b_h + 1572864;
    u16* T64a_h = T96a_h;
    u16* T64a_l = T96a_l;
    u16* T64b_h = T96b_h;
    u16* T64b_l = T96b_l;

    dim3 b256(256), b512(512);

    build_X<<<dim3(16, NPAIR), b256, 0, stream>>>(pc, alphas, X, sqX, T32a_h, T32a_l);
    hipMemsetAsync(deg, 0, 16384 * sizeof(float), stream);
    W_kernel<<<dim3(1024), b256, 0, stream>>>(X, sqX, sigp, deg, Whi);

    // ---- A-chain (D=32): A1, A2, A3, A4 -> M0 cols 0..31 ----
    apply_fused<32><<<dim3(512), b512, 0, stream>>>(Whi, T32a_h, T32a_l, deg,
                                             X, 32, 0, A1, 32, 0, nullptr, T32b_h, T32b_l, 0, 32);
    apply_fused<32><<<dim3(512), b512, 0, stream>>>(Whi, T32b_h, T32b_l, deg,
                                             A1, 32, 0, A2, 32, 0, nullptr, T32a_h, T32a_l, 0, 32);
    apply_fused<32><<<dim3(512), b512, 0, stream>>>(Whi, T32a_h, T32a_l, deg,
                                             A2, 32, 0, A3, 32, 0, nullptr, T32b_h, T32b_l, 0, 32);
    apply_fused<32><<<dim3(512), b512, 0, stream>>>(Whi, T32b_h, T32b_l, deg,
                                             A3, 32, 0, M0, 96, 0, nullptr, nullptr, nullptr, 0, 32);

    build_M0<<<dim3(16, NPAIR), b256, 0, stream>>>(A1, A2, M0, T96a_h, T96a_l);

    // ---- M-chain (D=96): M4 = P^4 M0; M2 cols 32..63 saved to M2p ----
    apply_fused<96><<<dim3(512), b512, 0, stream>>>(Whi, T96a_h, T96a_l, deg,
                                             M0, 96, 0, F96a, 96, 0, nullptr, T96b_h, T96b_l, 0, 96);
    apply_fused<96><<<dim3(512), b512, 0, stream>>>(Whi, T96b_h, T96b_l, deg,
                                             F96a, 96, 0, F96b, 96, 0, M2p, T96a_h, T96a_l, 0, 96);
    apply_fused<96><<<dim3(512), b512, 0, stream>>>(Whi, T96a_h, T96a_l, deg,
                                             F96b, 96, 0, F96a, 96, 0, nullptr, T96b_h, T96b_l, 0, 96);
    apply_fused<96><<<dim3(512), b512, 0, stream>>>(Whi, T96b_h, T96b_l, deg,
                                             F96a, 96, 0, M4f, 96, 0, nullptr, T64a_h, T64a_l, 32, 64);

    // ---- N-chain (D=64): Z8 = P^4 (M4 cols 32..95) ----
    apply_fused<64><<<dim3(512), b512, 0, stream>>>(Whi, T64a_h, T64a_l, deg,
                                             M4f, 96, 32, F96a, 64, 0, nullptr, T64b_h, T64b_l, 0, 64);
    apply_fused<64><<<dim3(512), b512, 0, stream>>>(Whi, T64b_h, T64b_l, deg,
                                             F96a, 64, 0, F96b, 64, 0, nullptr, T64a_h, T64a_l, 0, 64);
    apply_fused<64><<<dim3(512), b512, 0, stream>>>(Whi, T64a_h, T64a_l, deg,
                                             F96b, 64, 0, F96a, 64, 0, nullptr, T64b_h, T64b_l, 0, 64);
    apply_fused<64><<<dim3(512), b512, 0, stream>>>(Whi, T64b_h, T64b_l, deg,
                                             F96a, 64, 0, Z8, 64, 0, nullptr, nullptr, nullptr, 0, 64);

    hipMemsetAsync(out, 0, (size_t)NPAIR * 224 * sizeof(float), stream);
    pool_kernel<<<dim3(7, NPAIR, 8), dim3(32, 8), 0, stream>>>(X, M0, M2p, M4f, Z8, out);
}